// Round 1
// baseline (241.298 us; speedup 1.0000x reference)
//
#include <hip/hip_runtime.h>
#include <math.h>

typedef __attribute__((ext_vector_type(8))) short short8;
typedef __attribute__((ext_vector_type(4))) float f32x4;

#define NTOK 32768          // B*L
#define DDIM 1024
#define HDIM 64
#define NB 16
#define LN_EPS 1e-5f

#define IDX_OFF ((size_t)NTOK * NB)            // 524288
#define AUX_OFF (IDX_OFF + (size_t)NTOK * 2)   // 589824
#define WT_OFF  (AUX_OFF + 1)                  // 589825

// ws (float) layout:
//   [0:16)  cnt accum   [16:32) Psum accum   [32] completion counter (uint)
//   [64:128)  csg = colsum(gamma*W1)   [128:192) csb = colsum(beta*W1)
//   [4352 : +98304)   B-pack: 3 terms x 32 ksteps x 4 ntiles x 64 lanes x 4 dw
//   [102656 : +16384) per-pair partials: 512 rows x [0:16 cnt | 16:32 Psum]
#define CS_F   64
#define BP_F   4352
#define PART_F 102656

__device__ __forceinline__ short8 as_s8(uint4 u) {
    union { uint4 u; short8 s; } x; x.u = u; return x.s;
}

__device__ __forceinline__ f32x4 ntload4(const float* p) {
    return __builtin_nontemporal_load((const f32x4*)p);
}

// Fused: B-pack (3-term bf16 split of gamma*W1, MFMA B-frag order) + final
// colsums of gamma*W1 / beta*W1 via atomicAdd (ws[CS_F..] pre-zeroed).
// Also zeroes the per-pair partial region (router_main atomically accumulates
// into it now that two router blocks share one partial row).
__global__ void pack_kernel(const float* __restrict__ W1,
                            const float* __restrict__ gamma,
                            const float* __restrict__ beta,
                            float* __restrict__ ws) {
    __shared__ float sg[4][64];
    __shared__ float sb[4][64];
    const int s = blockIdx.x;           // k-range 32s..32s+31
    const int t = threadIdx.x;          // 256

    {   // zero partials: 32 blocks x 256 threads x 2 floats = 16384
        float* pz = ws + PART_F + ((size_t)s * 256 + t) * 2;
        pz[0] = 0.f; pz[1] = 0.f;
    }

    {   // cs partials
        const int j = t & 63, p = t >> 6;
        float ag = 0.f, ab = 0.f;
        for (int kk = 0; kk < 8; ++kk) {
            const int k = s * 32 + p * 8 + kk;
            const float w = W1[k * HDIM + j];
            ag += gamma[k] * w;
            ab += beta[k] * w;
        }
        sg[p][j] = ag;
        sb[p][j] = ab;
    }

    {   // B pack
        unsigned int* bp = (unsigned int*)(ws + BP_F);
        const int n = t >> 6;           // n-tile
        const int l = t & 63;           // frag lane
        const int q = l >> 4, c = l & 15;
        const int col = n * 16 + c;
        unsigned int uh[8], um[8], ul[8];
#pragma unroll
        for (int j = 0; j < 8; ++j) {
            const int k = s * 32 + q * 8 + j;
            const float w = gamma[k] * W1[k * HDIM + col];
            const unsigned int hb = __float_as_uint(w) & 0xFFFF0000u;
            const float r = w - __uint_as_float(hb);
            const unsigned int mb = __float_as_uint(r) & 0xFFFF0000u;
            const float r2 = r - __uint_as_float(mb);
            const unsigned int lb = __float_as_uint(r2) & 0xFFFF0000u;
            uh[j] = hb >> 16; um[j] = mb >> 16; ul[j] = lb >> 16;
        }
        const int base = ((s * 4 + n) * 64 + l) * 4;
#pragma unroll
        for (int d = 0; d < 4; ++d) {
            bp[base + d]         = uh[2 * d] | (uh[2 * d + 1] << 16);
            bp[32768 + base + d] = um[2 * d] | (um[2 * d + 1] << 16);
            bp[65536 + base + d] = ul[2 * d] | (ul[2 * d + 1] << 16);
        }
    }
    __syncthreads();
    if (t < 64) {
        atomicAdd(&ws[CS_F + t],      sg[0][t] + sg[1][t] + sg[2][t] + sg[3][t]);
        atomicAdd(&ws[CS_F + 64 + t], sb[0][t] + sb[1][t] + sb[2][t] + sb[3][t]);
    }
}

// 3-term truncated-bf16 split of 8 floats + LN-stat accumulation.
__device__ __forceinline__ void split8(const f32x4 a0, const f32x4 a1,
                                       short8& AH, short8& AM, short8& AL,
                                       float& s1, float& s2) {
    const float v[8] = {a0.x, a0.y, a0.z, a0.w, a1.x, a1.y, a1.z, a1.w};
    unsigned int ph[4], pm[4], pl[4];
#pragma unroll
    for (int d = 0; d < 4; ++d) {
        const float v0 = v[2 * d], v1 = v[2 * d + 1];
        const unsigned int h0 = __float_as_uint(v0) & 0xFFFF0000u;
        const unsigned int h1 = __float_as_uint(v1) & 0xFFFF0000u;
        const float r0 = v0 - __uint_as_float(h0);
        const float r1 = v1 - __uint_as_float(h1);
        const unsigned int m0 = __float_as_uint(r0) & 0xFFFF0000u;
        const unsigned int m1 = __float_as_uint(r1) & 0xFFFF0000u;
        const float q0 = r0 - __uint_as_float(m0);
        const float q1 = r1 - __uint_as_float(m1);
        ph[d] = (h0 >> 16) | h1;
        pm[d] = (m0 >> 16) | m1;
        pl[d] = (__float_as_uint(q0) >> 16) | (__float_as_uint(q1) & 0xFFFF0000u);
        s1 += v0 + v1;
        s2 = fmaf(v0, v0, fmaf(v1, v1, s2));
    }
    AH = as_s8(make_uint4(ph[0], ph[1], ph[2], ph[3]));
    AM = as_s8(make_uint4(pm[0], pm[1], pm[2], pm[3]));
    AL = as_s8(make_uint4(pl[0], pl[1], pl[2], pl[3]));
}

#define MFMA6(ACC, AH, AM, AL, BH, BM, BL)                                        \
    ACC = __builtin_amdgcn_mfma_f32_16x16x32_bf16(AH, as_s8(BH), ACC, 0, 0, 0);   \
    ACC = __builtin_amdgcn_mfma_f32_16x16x32_bf16(AH, as_s8(BM), ACC, 0, 0, 0);   \
    ACC = __builtin_amdgcn_mfma_f32_16x16x32_bf16(AM, as_s8(BH), ACC, 0, 0, 0);   \
    ACC = __builtin_amdgcn_mfma_f32_16x16x32_bf16(AH, as_s8(BL), ACC, 0, 0, 0);   \
    ACC = __builtin_amdgcn_mfma_f32_16x16x32_bf16(AM, as_s8(BM), ACC, 0, 0, 0);   \
    ACC = __builtin_amdgcn_mfma_f32_16x16x32_bf16(AL, as_s8(BH), ACC, 0, 0, 0);

// Block = 32 tokens, 4 waves. Wave wv owns k-quarter kh=wv (256 of 1024),
// all 32 tokens (two 16-row MFMA groups). 8 k-steps/wave.
// Grid = NTOK/32 = 1024 blocks -> 4 blocks/CU (vs 2 before): the kernel was
// latency-bound at 21.7% occupancy purely because grid == 2*numCU.
__global__ __launch_bounds__(256, 4)
void router_main(const float* __restrict__ x,
                 const float* __restrict__ ws_ro,       // csg/csb
                 const unsigned int* __restrict__ bp,   // packed B frags
                 const float* __restrict__ W2,
                 float* __restrict__ part,
                 float* __restrict__ out) {
    // smem (floats): ypart[4][32][65]=8320 | s1l[4][32] | s2l[4][32] |
    //                csgl 64 | csbl 64 | cntl 16
    // w2l aliases ypart[2] (+4160), llds aliases ypart[3] (+6240)
    __shared__ float smem[8736];
    float* ypart = smem;
    float* s1l   = smem + 8320;
    float* s2l   = smem + 8448;
    float* csgl  = smem + 8576;
    float* csbl  = smem + 8640;
    float* cntl  = smem + 8704;
    float* w2l   = smem + 4160;
    float* llds  = smem + 6240;

    const int t    = threadIdx.x;
    const int wv   = t >> 6;
    const int lane = t & 63;
    const int q = lane >> 4, c = lane & 15;
    const int kh = wv;                       // k-quarter
    const int tok0 = blockIdx.x * 32;

    if (t < 64) { csgl[t] = ws_ro[CS_F + t]; csbl[t] = ws_ro[CS_F + 64 + t]; }
    if (t < 16) cntl[t] = 0.f;

    const float* xr0 = x + (size_t)(tok0 + c) * DDIM + kh * 256 + q * 8;
    const float* xr1 = xr0 + (size_t)16 * DDIM;
    const unsigned int* bpl = bp + lane * 4;

    f32x4 acc0[4] = {{0.f,0.f,0.f,0.f},{0.f,0.f,0.f,0.f},{0.f,0.f,0.f,0.f},{0.f,0.f,0.f,0.f}};
    f32x4 acc1[4] = {{0.f,0.f,0.f,0.f},{0.f,0.f,0.f,0.f},{0.f,0.f,0.f,0.f},{0.f,0.f,0.f,0.f}};
    float s1a = 0.f, s2a = 0.f, s1b = 0.f, s2b = 0.f;

    // A: 2-step software pipeline, nontemporal (protect L2 for B-pack)
    f32x4 a00 = ntload4(xr0),      a01 = ntload4(xr0 + 4);
    f32x4 a10 = ntload4(xr1),      a11 = ntload4(xr1 + 4);
    f32x4 b00 = ntload4(xr0 + 32), b01 = ntload4(xr0 + 36);
    f32x4 b10 = ntload4(xr1 + 32), b11 = ntload4(xr1 + 36);

    for (int it = 0; it < 8; ++it) {
        const int s = kh * 8 + it;

        // B loads first — split8's VALU work below covers their L2 latency
        uint4 bh[4], bm[4], bl[4];
#pragma unroll
        for (int n = 0; n < 4; ++n) {
            bh[n] = *(const uint4*)(bpl + (s * 4 + n) * 256);
            bm[n] = *(const uint4*)(bpl + 32768 + (s * 4 + n) * 256);
            bl[n] = *(const uint4*)(bpl + 65536 + (s * 4 + n) * 256);
        }
        // A prefetch 2 steps ahead
        const int off = ((it + 2) & 7) * 32;
        const f32x4 p00 = ntload4(xr0 + off), p01 = ntload4(xr0 + off + 4);
        const f32x4 p10 = ntload4(xr1 + off), p11 = ntload4(xr1 + off + 4);

        short8 AH0, AM0, AL0, AH1, AM1, AL1;
        split8(a00, a01, AH0, AM0, AL0, s1a, s2a);
        split8(a10, a11, AH1, AM1, AL1, s1b, s2b);

#pragma unroll
        for (int n = 0; n < 4; ++n) {
            MFMA6(acc0[n], AH0, AM0, AL0, bh[n], bm[n], bl[n]);
            MFMA6(acc1[n], AH1, AM1, AL1, bh[n], bm[n], bl[n]);
        }
        a00 = b00; a01 = b01; a10 = b10; a11 = b11;
        b00 = p00; b01 = p01; b10 = p10; b11 = p11;
    }

    // LN-stat q-reduction (per token, this wave's k-quarter)
    s1a += __shfl_xor(s1a, 16, 64); s1a += __shfl_xor(s1a, 32, 64);
    s2a += __shfl_xor(s2a, 16, 64); s2a += __shfl_xor(s2a, 32, 64);
    s1b += __shfl_xor(s1b, 16, 64); s1b += __shfl_xor(s1b, 32, 64);
    s2b += __shfl_xor(s2b, 16, 64); s2b += __shfl_xor(s2b, 32, 64);
    if (lane < 16) {
        s1l[wv * 32 + c] = s1a;      s2l[wv * 32 + c] = s2a;
        s1l[wv * 32 + 16 + c] = s1b; s2l[wv * 32 + 16 + c] = s2b;
    }

    // partial acc -> LDS  (C/D: row = q*4+r, col = n*16+c)
#pragma unroll
    for (int n = 0; n < 4; ++n)
#pragma unroll
        for (int r = 0; r < 4; ++r) {
            ypart[wv * 2080 + (q * 4 + r) * 65 + n * 16 + c]      = acc0[n][r];
            ypart[wv * 2080 + (16 + q * 4 + r) * 65 + n * 16 + c] = acc1[n][r];
        }
    __syncthreads();

    // 4-way k-quarter combine + LN fold + exact GELU.
    // thread: token m = t>>3, 8 cols starting (t&7)*8
    {
        const int m = t >> 3, cb = (t & 7) * 8;
        const float S1 = s1l[m] + s1l[32 + m] + s1l[64 + m] + s1l[96 + m];
        const float S2 = s2l[m] + s2l[32 + m] + s2l[64 + m] + s2l[96 + m];
        const float mu   = S1 * (1.0f / 1024.0f);
        const float var  = S2 * (1.0f / 1024.0f) - mu * mu;
        const float rstd = 1.0f / sqrtf(var + LN_EPS);
#pragma unroll
        for (int cc = 0; cc < 8; ++cc) {
            const int col = cb + cc;
            const float y = ypart[m * 65 + col]
                          + ypart[2080 + m * 65 + col]
                          + ypart[4160 + m * 65 + col]
                          + ypart[6240 + m * 65 + col];
            const float pre = rstd * (y - mu * csgl[col]) + csbl[col];
            ypart[m * 65 + col] =
                0.5f * pre * (1.0f + erff(pre * 0.70710678118654752f));
        }
    }
    __syncthreads();

    // stage W2 -> LDS (aliases ypart[2], dead after combine)
    {
        const float4 wv4 = *(const float4*)(W2 + t * 4);
        const int j = t >> 2, gq = (t & 3) * 4;
        w2l[j * 17 + gq + 0] = wv4.x; w2l[j * 17 + gq + 1] = wv4.y;
        w2l[j * 17 + gq + 2] = wv4.z; w2l[j * 17 + gq + 3] = wv4.w;
    }
    __syncthreads();

    // logits: thread -> (token m2 = t>>3, 2 blocks)
    {
        const int m2 = t >> 3, nb0 = (t & 7) * 2;
        const float* hrow = ypart + m2 * 65;
        float l0 = 0.f, l1 = 0.f;
#pragma unroll
        for (int j = 0; j < 64; ++j) {
            const float h = hrow[j];
            l0 = fmaf(h, w2l[j * 17 + nb0 + 0], l0);
            l1 = fmaf(h, w2l[j * 17 + nb0 + 1], l1);
        }
        llds[m2 * 17 + nb0 + 0] = l0 * 0.5f;   // /TEMP
        llds[m2 * 17 + nb0 + 1] = l1 * 0.5f;
    }
    __syncthreads();

    // softmax + top-2 + outputs (one thread per token)
    if (t < 32) {
        float p[16];
        float mx = -1e30f;
#pragma unroll
        for (int i = 0; i < NB; ++i) { p[i] = llds[t * 17 + i]; mx = fmaxf(mx, p[i]); }
        float s = 0.f;
#pragma unroll
        for (int i = 0; i < NB; ++i) { p[i] = expf(p[i] - mx); s += p[i]; }
        const float inv = 1.0f / s;
#pragma unroll
        for (int i = 0; i < NB; ++i) { p[i] *= inv; llds[t * 17 + i] = p[i]; }

        float* po = out + (size_t)(tok0 + t) * NB;
#pragma unroll
        for (int u = 0; u < 4; ++u) {
            float4 v; v.x = p[u*4]; v.y = p[u*4+1]; v.z = p[u*4+2]; v.w = p[u*4+3];
            *(float4*)(po + u * 4) = v;
        }

        float b0 = -1.f, b1 = -1.f;
        int i0 = 0, i1 = 0;
#pragma unroll
        for (int i = 0; i < NB; ++i) {
            if (p[i] > b0)      { b1 = b0; i1 = i0; b0 = p[i]; i0 = i; }
            else if (p[i] > b1) { b1 = p[i]; i1 = i; }
        }
        const float wsum = b0 + b1 + 1e-8f;
        out[IDX_OFF + (size_t)(tok0 + t) * 2]     = (float)i0;
        out[IDX_OFF + (size_t)(tok0 + t) * 2 + 1] = (float)i1;
        out[WT_OFF + (size_t)(tok0 + t) * 2]      = b0 / wsum;
        out[WT_OFF + (size_t)(tok0 + t) * 2 + 1]  = b1 / wsum;
        atomicAdd(&cntl[i0], 1.0f);
        atomicAdd(&cntl[i1], 1.0f);
    }
    __syncthreads();

    // per-pair partials: two blocks share one row via atomicAdd
    // (pack_kernel pre-zeroes the region; aux reads after dispatch boundary)
    if (t < 16) {
        float ps = 0.f;
        for (int m = 0; m < 32; ++m) ps += llds[m * 17 + t];
        const size_t row = (size_t)(blockIdx.x >> 1) * 32;
        atomicAdd(&part[row + 16 + t], ps);
        atomicAdd(&part[row + t], cntl[t]);
    }
}

__global__ void aux_kernel(const float* __restrict__ part,
                           float* __restrict__ gacc,
                           float* __restrict__ out) {
    __shared__ float red[8][32];
    __shared__ float flag;
    const int t = threadIdx.x;          // 256
    const int b = blockIdx.x;           // 32 blocks x 16 rows
    const int i = t & 31, rr = t >> 5;  // rr 0..7
    const int r0 = b * 16 + rr;
    red[rr][i] = part[(size_t)r0 * 32 + i] + part[(size_t)(r0 + 8) * 32 + i];
    __syncthreads();
    if (t < 32) {
        float tot = 0.f;
#pragma unroll
        for (int p = 0; p < 8; ++p) tot += red[p][t];
        atomicAdd(&gacc[t], tot);
    }
    __syncthreads();
    if (t == 0) {
        __threadfence();
        const unsigned int old = atomicAdd((unsigned int*)(gacc + 32), 1u);
        flag = (old == 31u) ? 1.f : 0.f;
    }
    __syncthreads();
    if (flag != 0.f) {
        if (t < 32) red[0][t] = atomicAdd(&gacc[t], 0.0f);   // coherent read
        __syncthreads();
        if (t == 0) {
            float a = 0.f;
            for (int k = 0; k < NB; ++k) {
                const float f = red[0][k] / (65536.0f + 1e-8f);
                const float P = red[0][16 + k] * (1.0f / 32768.0f);
                a += f * P;
            }
            out[AUX_OFF] = 16.0f * a;
        }
    }
}

extern "C" void kernel_launch(void* const* d_in, const int* in_sizes, int n_in,
                              void* d_out, int out_size, void* d_ws, size_t ws_size,
                              hipStream_t stream) {
    const float* x     = (const float*)d_in[0];
    const float* gamma = (const float*)d_in[1];
    const float* beta  = (const float*)d_in[2];
    const float* W1    = (const float*)d_in[3];
    const float* W2    = (const float*)d_in[4];
    float* out = (float*)d_out;
    float* ws  = (float*)d_ws;

    (void)hipMemsetAsync(ws, 0, 192 * sizeof(float), stream);  // accums + counter + cs
    pack_kernel<<<32, 256, 0, stream>>>(W1, gamma, beta, ws);
    router_main<<<NTOK / 32, 256, 0, stream>>>(x, ws, (const unsigned int*)(ws + BP_F),
                                               W2, ws + PART_F, out);
    aux_kernel<<<32, 256, 0, stream>>>(ws + PART_F, ws, out);
}

// Round 2
// 230.033 us; speedup vs baseline: 1.0490x; 1.0490x over previous
//
#include <hip/hip_runtime.h>
#include <math.h>

typedef __attribute__((ext_vector_type(8))) short short8;
typedef __attribute__((ext_vector_type(4))) float f32x4;

#define NTOK 32768          // B*L
#define DDIM 1024
#define HDIM 64
#define NB 16
#define LN_EPS 1e-5f

#define IDX_OFF ((size_t)NTOK * NB)            // 524288
#define AUX_OFF (IDX_OFF + (size_t)NTOK * 2)   // 589824
#define WT_OFF  (AUX_OFF + 1)                  // 589825

// ws (float) layout:
//   [0:16)  cnt accum   [16:32) Psum accum   [32] completion counter (uint)
//   [64:128)  csg = colsum(gamma*W1)   [128:192) csb = colsum(beta*W1)
//   [4352 : +98304)   B-pack: 3 terms x 32 ksteps x 4 ntiles x 64 lanes x 4 dw
//   [102656 : +8192)  per-block partials: 256 rows x [0:16 cnt | 16:32 Psum]
#define CS_F   64
#define BP_F   4352
#define PART_F 102656

__device__ __forceinline__ short8 as_s8(uint4 u) {
    union { uint4 u; short8 s; } x; x.u = u; return x.s;
}

__device__ __forceinline__ f32x4 ntload4(const float* p) {
    return __builtin_nontemporal_load((const f32x4*)p);
}

// Fused: B-pack (3-term bf16 split of gamma*W1, MFMA B-frag order) + final
// colsums of gamma*W1 / beta*W1 via atomicAdd (ws[CS_F..] pre-zeroed).
__global__ void pack_kernel(const float* __restrict__ W1,
                            const float* __restrict__ gamma,
                            const float* __restrict__ beta,
                            float* __restrict__ ws) {
    __shared__ float sg[4][64];
    __shared__ float sb[4][64];
    const int s = blockIdx.x;           // k-range 32s..32s+31
    const int t = threadIdx.x;          // 256

    {   // cs partials
        const int j = t & 63, p = t >> 6;
        float ag = 0.f, ab = 0.f;
        for (int kk = 0; kk < 8; ++kk) {
            const int k = s * 32 + p * 8 + kk;
            const float w = W1[k * HDIM + j];
            ag += gamma[k] * w;
            ab += beta[k] * w;
        }
        sg[p][j] = ag;
        sb[p][j] = ab;
    }

    {   // B pack
        unsigned int* bp = (unsigned int*)(ws + BP_F);
        const int n = t >> 6;           // n-tile
        const int l = t & 63;           // frag lane
        const int q = l >> 4, c = l & 15;
        const int col = n * 16 + c;
        unsigned int uh[8], um[8], ul[8];
#pragma unroll
        for (int j = 0; j < 8; ++j) {
            const int k = s * 32 + q * 8 + j;
            const float w = gamma[k] * W1[k * HDIM + col];
            const unsigned int hb = __float_as_uint(w) & 0xFFFF0000u;
            const float r = w - __uint_as_float(hb);
            const unsigned int mb = __float_as_uint(r) & 0xFFFF0000u;
            const float r2 = r - __uint_as_float(mb);
            const unsigned int lb = __float_as_uint(r2) & 0xFFFF0000u;
            uh[j] = hb >> 16; um[j] = mb >> 16; ul[j] = lb >> 16;
        }
        const int base = ((s * 4 + n) * 64 + l) * 4;
#pragma unroll
        for (int d = 0; d < 4; ++d) {
            bp[base + d]         = uh[2 * d] | (uh[2 * d + 1] << 16);
            bp[32768 + base + d] = um[2 * d] | (um[2 * d + 1] << 16);
            bp[65536 + base + d] = ul[2 * d] | (ul[2 * d + 1] << 16);
        }
    }
    __syncthreads();
    if (t < 64) {
        atomicAdd(&ws[CS_F + t],      sg[0][t] + sg[1][t] + sg[2][t] + sg[3][t]);
        atomicAdd(&ws[CS_F + 64 + t], sb[0][t] + sb[1][t] + sb[2][t] + sb[3][t]);
    }
}

// 3-term truncated-bf16 split of 8 floats + LN-stat accumulation.
__device__ __forceinline__ void split8(const f32x4 a0, const f32x4 a1,
                                       short8& AH, short8& AM, short8& AL,
                                       float& s1, float& s2) {
    const float v[8] = {a0.x, a0.y, a0.z, a0.w, a1.x, a1.y, a1.z, a1.w};
    unsigned int ph[4], pm[4], pl[4];
#pragma unroll
    for (int d = 0; d < 4; ++d) {
        const float v0 = v[2 * d], v1 = v[2 * d + 1];
        const unsigned int h0 = __float_as_uint(v0) & 0xFFFF0000u;
        const unsigned int h1 = __float_as_uint(v1) & 0xFFFF0000u;
        const float r0 = v0 - __uint_as_float(h0);
        const float r1 = v1 - __uint_as_float(h1);
        const unsigned int m0 = __float_as_uint(r0) & 0xFFFF0000u;
        const unsigned int m1 = __float_as_uint(r1) & 0xFFFF0000u;
        const float q0 = r0 - __uint_as_float(m0);
        const float q1 = r1 - __uint_as_float(m1);
        ph[d] = (h0 >> 16) | h1;
        pm[d] = (m0 >> 16) | m1;
        pl[d] = (__float_as_uint(q0) >> 16) | (__float_as_uint(q1) & 0xFFFF0000u);
        s1 += v0 + v1;
        s2 = fmaf(v0, v0, fmaf(v1, v1, s2));
    }
    AH = as_s8(make_uint4(ph[0], ph[1], ph[2], ph[3]));
    AM = as_s8(make_uint4(pm[0], pm[1], pm[2], pm[3]));
    AL = as_s8(make_uint4(pl[0], pl[1], pl[2], pl[3]));
}

#define MFMA6(ACC, AH, AM, AL, BH, BM, BL)                                        \
    ACC = __builtin_amdgcn_mfma_f32_16x16x32_bf16(AH, as_s8(BH), ACC, 0, 0, 0);   \
    ACC = __builtin_amdgcn_mfma_f32_16x16x32_bf16(AH, as_s8(BM), ACC, 0, 0, 0);   \
    ACC = __builtin_amdgcn_mfma_f32_16x16x32_bf16(AM, as_s8(BH), ACC, 0, 0, 0);   \
    ACC = __builtin_amdgcn_mfma_f32_16x16x32_bf16(AH, as_s8(BL), ACC, 0, 0, 0);   \
    ACC = __builtin_amdgcn_mfma_f32_16x16x32_bf16(AM, as_s8(BM), ACC, 0, 0, 0);   \
    ACC = __builtin_amdgcn_mfma_f32_16x16x32_bf16(AL, as_s8(BH), ACC, 0, 0, 0);

// One k-step: read B frags from LDS buffer CUR, MFMA, swap A pipeline,
// stage step S+1's B (loaded early into regs) into NXT, barrier.
#define STEP(S, CUR, NXT, DOSTAGE)                                               \
    {                                                                            \
        const int off = (((S) + 2) & 31) * 32;                                   \
        const f32x4 p00 = ntload4(xr0 + off), p01 = ntload4(xr0 + off + 4);      \
        const f32x4 p10 = ntload4(xr1 + off), p11 = ntload4(xr1 + off + 4);      \
        uint4 st0, st1, st2;                                                     \
        if (DOSTAGE) {                                                           \
            const unsigned int* sp = bp + ((S) + 1) * 1024 + t * 4;              \
            st0 = *(const uint4*)(sp);                                           \
            st1 = *(const uint4*)(sp + 32768);                                   \
            st2 = *(const uint4*)(sp + 65536);                                   \
        }                                                                        \
        short8 AH0, AM0, AL0, AH1, AM1, AL1;                                     \
        split8(a00, a01, AH0, AM0, AL0, s1a, s2a);                               \
        split8(a10, a11, AH1, AM1, AL1, s1b, s2b);                               \
        _Pragma("unroll")                                                        \
        for (int n = 0; n < 4; ++n) {                                            \
            const uint4 bh = *(const uint4*)((CUR) + n * 256 + lane * 4);        \
            const uint4 bm = *(const uint4*)((CUR) + 1024 + n * 256 + lane * 4); \
            const uint4 bl = *(const uint4*)((CUR) + 2048 + n * 256 + lane * 4); \
            MFMA6(acc0[n], AH0, AM0, AL0, bh, bm, bl);                           \
            MFMA6(acc1[n], AH1, AM1, AL1, bh, bm, bl);                           \
        }                                                                        \
        a00 = b00; a01 = b01; a10 = b10; a11 = b11;                              \
        b00 = p00; b01 = p01; b10 = p10; b11 = p11;                              \
        if (DOSTAGE) {                                                           \
            *(uint4*)((NXT) + t * 4)        = st0;                               \
            *(uint4*)((NXT) + 1024 + t * 4) = st1;                               \
            *(uint4*)((NXT) + 2048 + t * 4) = st2;                               \
        }                                                                        \
        __syncthreads();                                                         \
    }

// Block = 128 tokens, 4 waves; wave wv owns tokens [wv*32, wv*32+32) and
// iterates the FULL K=1024 (32 k-steps). B-pack is shared across waves via
// a 12 KB x 2 LDS double-buffer (one barrier per k-step). Accumulators are
// complete after the loop -> no cross-wave combine; LN stats redistribute
// in-register via shfl. Grid = 256 = 1 block/CU, 2 waves/SIMD (m97 regime:
// latency hidden by the LDS pipeline, not TLP).
__global__ __launch_bounds__(256, 2)
void router_main(const float* __restrict__ x,
                 const float* __restrict__ ws_ro,       // csg/csb
                 const unsigned int* __restrict__ bp,   // packed B frags
                 const float* __restrict__ W2,
                 float* __restrict__ part,
                 float* __restrict__ out) {
    // smem (floats): bstage[2][3072]=6144 | hlds[4][32][65]=8320 | cntl 16
    // w2l (64x16) aliases bstage[0..1024); llds (128x16) aliases bstage[1024..3072)
    // (buf0 is dead during step 31, which reads buf1 only)
    __shared__ __align__(16) float smem[14480];
    float* bstage = smem;
    float* hlds   = smem + 6144;
    float* cntl   = smem + 14464;
    float* w2l    = smem;
    float* llds   = smem + 1024;

    const int t    = threadIdx.x;
    const int wv   = t >> 6;
    const int lane = t & 63;
    const int q = lane >> 4, c = lane & 15;
    const int tok0 = blockIdx.x * 128;
    const int tokw = tok0 + wv * 32;

    if (t < 16) cntl[t] = 0.f;

    // per-lane colsum constants (col = n*16 + c) — registers, no LDS staging
    float csg[4], csb[4];
#pragma unroll
    for (int n = 0; n < 4; ++n) {
        csg[n] = ws_ro[CS_F + n * 16 + c];
        csb[n] = ws_ro[CS_F + 64 + n * 16 + c];
    }

    const float* xr0 = x + (size_t)(tokw + c) * DDIM + q * 8;
    const float* xr1 = xr0 + (size_t)16 * DDIM;

    // prologue: stage step 0 B (12 KB) into buf0. thread t -> term j, 16 B.
    {
        uint4 s0 = *(const uint4*)(bp + t * 4);
        uint4 s1 = *(const uint4*)(bp + 32768 + t * 4);
        uint4 s2 = *(const uint4*)(bp + 65536 + t * 4);
        *(uint4*)(bstage + t * 4)        = s0;
        *(uint4*)(bstage + 1024 + t * 4) = s1;
        *(uint4*)(bstage + 2048 + t * 4) = s2;
    }

    f32x4 acc0[4] = {{0.f,0.f,0.f,0.f},{0.f,0.f,0.f,0.f},{0.f,0.f,0.f,0.f},{0.f,0.f,0.f,0.f}};
    f32x4 acc1[4] = {{0.f,0.f,0.f,0.f},{0.f,0.f,0.f,0.f},{0.f,0.f,0.f,0.f},{0.f,0.f,0.f,0.f}};
    float s1a = 0.f, s2a = 0.f, s1b = 0.f, s2b = 0.f;

    // A: 2-step register pipeline, nontemporal (protect L2 for B-pack)
    f32x4 a00 = ntload4(xr0),      a01 = ntload4(xr0 + 4);
    f32x4 a10 = ntload4(xr1),      a11 = ntload4(xr1 + 4);
    f32x4 b00 = ntload4(xr0 + 32), b01 = ntload4(xr0 + 36);
    f32x4 b10 = ntload4(xr1 + 32), b11 = ntload4(xr1 + 36);

    __syncthreads();   // buf0 visible

    float* const bufA = bstage;
    float* const bufB = bstage + 3072;
#pragma unroll 1
    for (int s2i = 0; s2i < 16; ++s2i) {
        const int s = s2i * 2;
        STEP(s,     bufA, bufB, 1)
        STEP(s + 1, bufB, bufA, (s2i < 15))
    }

    // LN-stat q-reduction: lane (q,c) holds k-quarter partials for token
    // tokw+c (a) / tokw+16+c (b); xor 16/32 combines the 4 q replicas.
    s1a += __shfl_xor(s1a, 16, 64); s1a += __shfl_xor(s1a, 32, 64);
    s2a += __shfl_xor(s2a, 16, 64); s2a += __shfl_xor(s2a, 32, 64);
    s1b += __shfl_xor(s1b, 16, 64); s1b += __shfl_xor(s1b, 32, 64);
    s2b += __shfl_xor(s2b, 16, 64); s2b += __shfl_xor(s2b, 32, 64);

    // W2 -> LDS (row-major 64x16), aliases buf0 head (dead after main loop)
    *(float4*)(w2l + t * 4) = *(const float4*)(W2 + t * 4);

    // stats redistribution (token tt stats live at lane tt) + LN fold +
    // exact GELU, straight from accumulator registers -> h to LDS.
    {
        float* hw = hlds + wv * 2080;
#pragma unroll
        for (int r = 0; r < 4; ++r) {
            const int tt = q * 4 + r;
            const float S1A = __shfl(s1a, tt, 64), S2A = __shfl(s2a, tt, 64);
            const float S1B = __shfl(s1b, tt, 64), S2B = __shfl(s2b, tt, 64);
            const float muA = S1A * (1.0f / 1024.0f);
            const float rsA = 1.0f / sqrtf(S2A * (1.0f / 1024.0f) - muA * muA + LN_EPS);
            const float muB = S1B * (1.0f / 1024.0f);
            const float rsB = 1.0f / sqrtf(S2B * (1.0f / 1024.0f) - muB * muB + LN_EPS);
#pragma unroll
            for (int n = 0; n < 4; ++n) {
                const float preA = rsA * (acc0[n][r] - muA * csg[n]) + csb[n];
                const float preB = rsB * (acc1[n][r] - muB * csg[n]) + csb[n];
                hw[tt * 65 + n * 16 + c] =
                    0.5f * preA * (1.0f + erff(preA * 0.70710678118654752f));
                hw[(16 + tt) * 65 + n * 16 + c] =
                    0.5f * preB * (1.0f + erff(preB * 0.70710678118654752f));
            }
        }
    }
    __syncthreads();

    // logits: thread -> (token m2 = t>>1, nb-octet). w2l reads are wave-
    // uniform (broadcast, conflict-free); hrow reads stride-65 (conflict-free).
    {
        const int m2 = t >> 1, o = (t & 1) * 8;
        const float* hrow = hlds + (m2 >> 5) * 2080 + (m2 & 31) * 65;
        f32x4 L0 = {0.f, 0.f, 0.f, 0.f}, L1 = {0.f, 0.f, 0.f, 0.f};
#pragma unroll 8
        for (int j = 0; j < 64; ++j) {
            const float h = hrow[j];
            L0 += *(const f32x4*)(w2l + j * 16 + o) * h;
            L1 += *(const f32x4*)(w2l + j * 16 + o + 4) * h;
        }
        *(f32x4*)(llds + m2 * 16 + o)     = L0 * 0.5f;   // /TEMP
        *(f32x4*)(llds + m2 * 16 + o + 4) = L1 * 0.5f;
    }
    __syncthreads();

    // softmax + top-2 + outputs (one thread per token; 128 tokens/block)
    if (t < 128) {
        float p[16];
        float mx = -1e30f;
#pragma unroll
        for (int i = 0; i < NB; ++i) { p[i] = llds[t * 16 + i]; mx = fmaxf(mx, p[i]); }
        float ssum = 0.f;
#pragma unroll
        for (int i = 0; i < NB; ++i) { p[i] = expf(p[i] - mx); ssum += p[i]; }
        const float inv = 1.0f / ssum;
#pragma unroll
        for (int i = 0; i < NB; ++i) { p[i] *= inv; llds[t * 16 + i] = p[i]; }

        float* po = out + (size_t)(tok0 + t) * NB;
#pragma unroll
        for (int u = 0; u < 4; ++u) {
            float4 v; v.x = p[u*4]; v.y = p[u*4+1]; v.z = p[u*4+2]; v.w = p[u*4+3];
            *(float4*)(po + u * 4) = v;
        }

        float b0 = -1.f, b1 = -1.f;
        int i0 = 0, i1 = 0;
#pragma unroll
        for (int i = 0; i < NB; ++i) {
            if (p[i] > b0)      { b1 = b0; i1 = i0; b0 = p[i]; i0 = i; }
            else if (p[i] > b1) { b1 = p[i]; i1 = i; }
        }
        const float wsum = b0 + b1 + 1e-8f;
        out[IDX_OFF + (size_t)(tok0 + t) * 2]     = (float)i0;
        out[IDX_OFF + (size_t)(tok0 + t) * 2 + 1] = (float)i1;
        out[WT_OFF + (size_t)(tok0 + t) * 2]      = b0 / wsum;
        out[WT_OFF + (size_t)(tok0 + t) * 2 + 1]  = b1 / wsum;
        atomicAdd(&cntl[i0], 1.0f);
        atomicAdd(&cntl[i1], 1.0f);
    }
    __syncthreads();

    // per-block partials (plain stores; aux reads after dispatch boundary)
    if (t < 16) {
        float ps = 0.f;
        for (int m = 0; m < 128; ++m) ps += llds[m * 16 + t];
        part[(size_t)blockIdx.x * 32 + t]      = cntl[t];
        part[(size_t)blockIdx.x * 32 + 16 + t] = ps;
    }
}

__global__ void aux_kernel(const float* __restrict__ part,
                           float* __restrict__ gacc,
                           float* __restrict__ out) {
    __shared__ float red[8][32];
    __shared__ float flag;
    const int t = threadIdx.x;          // 256
    const int b = blockIdx.x;           // 16 blocks x 16 rows
    const int i = t & 31, rr = t >> 5;  // rr 0..7
    const int r0 = b * 16 + rr;
    red[rr][i] = part[(size_t)r0 * 32 + i] + part[(size_t)(r0 + 8) * 32 + i];
    __syncthreads();
    if (t < 32) {
        float tot = 0.f;
#pragma unroll
        for (int p = 0; p < 8; ++p) tot += red[p][t];
        atomicAdd(&gacc[t], tot);
    }
    __syncthreads();
    if (t == 0) {
        __threadfence();
        const unsigned int old = atomicAdd((unsigned int*)(gacc + 32), 1u);
        flag = (old == 15u) ? 1.f : 0.f;
    }
    __syncthreads();
    if (flag != 0.f) {
        if (t < 32) red[0][t] = atomicAdd(&gacc[t], 0.0f);   // coherent read
        __syncthreads();
        if (t == 0) {
            float a = 0.f;
            for (int k = 0; k < NB; ++k) {
                const float f = red[0][k] / (65536.0f + 1e-8f);
                const float P = red[0][16 + k] * (1.0f / 32768.0f);
                a += f * P;
            }
            out[AUX_OFF] = 16.0f * a;
        }
    }
}

extern "C" void kernel_launch(void* const* d_in, const int* in_sizes, int n_in,
                              void* d_out, int out_size, void* d_ws, size_t ws_size,
                              hipStream_t stream) {
    const float* x     = (const float*)d_in[0];
    const float* gamma = (const float*)d_in[1];
    const float* beta  = (const float*)d_in[2];
    const float* W1    = (const float*)d_in[3];
    const float* W2    = (const float*)d_in[4];
    float* out = (float*)d_out;
    float* ws  = (float*)d_ws;

    (void)hipMemsetAsync(ws, 0, 192 * sizeof(float), stream);  // accums + counter + cs
    pack_kernel<<<32, 256, 0, stream>>>(W1, gamma, beta, ws);
    router_main<<<NTOK / 128, 256, 0, stream>>>(x, ws, (const unsigned int*)(ws + BP_F),
                                                W2, ws + PART_F, out);
    aux_kernel<<<16, 256, 0, stream>>>(ws + PART_F, ws, out);
}

// Round 3
// 227.594 us; speedup vs baseline: 1.0602x; 1.0107x over previous
//
#include <hip/hip_runtime.h>
#include <math.h>

typedef __attribute__((ext_vector_type(8))) short short8;
typedef __attribute__((ext_vector_type(4))) float f32x4;

#define NTOK 32768          // B*L
#define DDIM 1024
#define HDIM 64
#define NB 16
#define LN_EPS 1e-5f

#define IDX_OFF ((size_t)NTOK * NB)            // 524288
#define AUX_OFF (IDX_OFF + (size_t)NTOK * 2)   // 589824
#define WT_OFF  (AUX_OFF + 1)                  // 589825

// ws (float) layout:
//   [0:16)  cnt accum   [16:32) Psum accum   [32] completion counter (uint)
//   [64:128)  csg = colsum(gamma*W1)   [128:192) csb = colsum(beta*W1)
//   [4352 : +98304)   B-pack: 3 terms x 32 ksteps x 4 ntiles x 64 lanes x 4 dw
//   [102656 : +16384) per-block partials: 512 rows x [0:16 cnt | 16:32 Psum]
#define CS_F   64
#define BP_F   4352
#define PART_F 102656

__device__ __forceinline__ short8 as_s8(uint4 u) {
    union { uint4 u; short8 s; } x; x.u = u; return x.s;
}

__device__ __forceinline__ f32x4 ntload4(const float* p) {
    return __builtin_nontemporal_load((const f32x4*)p);
}

// async global->LDS, 16B per lane. LDS dest is wave-uniform base + lane*16;
// global src is per-lane. B-pack layout is linear in lane order, so this is
// a drop-in replacement for the reg-staged ds_write path.
__device__ __forceinline__ void gld16(const unsigned int* g, float* l) {
    __builtin_amdgcn_global_load_lds(
        (const __attribute__((address_space(1))) void*)g,
        (__attribute__((address_space(3))) void*)l, 16, 0, 0);
}

// Fused: B-pack (3-term bf16 split of gamma*W1, MFMA B-frag order) + final
// colsums of gamma*W1 / beta*W1 via atomicAdd (ws[CS_F..] pre-zeroed).
__global__ void pack_kernel(const float* __restrict__ W1,
                            const float* __restrict__ gamma,
                            const float* __restrict__ beta,
                            float* __restrict__ ws) {
    __shared__ float sg[4][64];
    __shared__ float sb[4][64];
    const int s = blockIdx.x;           // k-range 32s..32s+31
    const int t = threadIdx.x;          // 256

    {   // cs partials
        const int j = t & 63, p = t >> 6;
        float ag = 0.f, ab = 0.f;
        for (int kk = 0; kk < 8; ++kk) {
            const int k = s * 32 + p * 8 + kk;
            const float w = W1[k * HDIM + j];
            ag += gamma[k] * w;
            ab += beta[k] * w;
        }
        sg[p][j] = ag;
        sb[p][j] = ab;
    }

    {   // B pack
        unsigned int* bp = (unsigned int*)(ws + BP_F);
        const int n = t >> 6;           // n-tile
        const int l = t & 63;           // frag lane
        const int q = l >> 4, c = l & 15;
        const int col = n * 16 + c;
        unsigned int uh[8], um[8], ul[8];
#pragma unroll
        for (int j = 0; j < 8; ++j) {
            const int k = s * 32 + q * 8 + j;
            const float w = gamma[k] * W1[k * HDIM + col];
            const unsigned int hb = __float_as_uint(w) & 0xFFFF0000u;
            const float r = w - __uint_as_float(hb);
            const unsigned int mb = __float_as_uint(r) & 0xFFFF0000u;
            const float r2 = r - __uint_as_float(mb);
            const unsigned int lb = __float_as_uint(r2) & 0xFFFF0000u;
            uh[j] = hb >> 16; um[j] = mb >> 16; ul[j] = lb >> 16;
        }
        const int base = ((s * 4 + n) * 64 + l) * 4;
#pragma unroll
        for (int d = 0; d < 4; ++d) {
            bp[base + d]         = uh[2 * d] | (uh[2 * d + 1] << 16);
            bp[32768 + base + d] = um[2 * d] | (um[2 * d + 1] << 16);
            bp[65536 + base + d] = ul[2 * d] | (ul[2 * d + 1] << 16);
        }
    }
    __syncthreads();
    if (t < 64) {
        atomicAdd(&ws[CS_F + t],      sg[0][t] + sg[1][t] + sg[2][t] + sg[3][t]);
        atomicAdd(&ws[CS_F + 64 + t], sb[0][t] + sb[1][t] + sb[2][t] + sb[3][t]);
    }
}

// 3-term truncated-bf16 split of 8 floats + LN-stat accumulation.
__device__ __forceinline__ void split8(const f32x4 a0, const f32x4 a1,
                                       short8& AH, short8& AM, short8& AL,
                                       float& s1, float& s2) {
    const float v[8] = {a0.x, a0.y, a0.z, a0.w, a1.x, a1.y, a1.z, a1.w};
    unsigned int ph[4], pm[4], pl[4];
#pragma unroll
    for (int d = 0; d < 4; ++d) {
        const float v0 = v[2 * d], v1 = v[2 * d + 1];
        const unsigned int h0 = __float_as_uint(v0) & 0xFFFF0000u;
        const unsigned int h1 = __float_as_uint(v1) & 0xFFFF0000u;
        const float r0 = v0 - __uint_as_float(h0);
        const float r1 = v1 - __uint_as_float(h1);
        const unsigned int m0 = __float_as_uint(r0) & 0xFFFF0000u;
        const unsigned int m1 = __float_as_uint(r1) & 0xFFFF0000u;
        const float q0 = r0 - __uint_as_float(m0);
        const float q1 = r1 - __uint_as_float(m1);
        ph[d] = (h0 >> 16) | h1;
        pm[d] = (m0 >> 16) | m1;
        pl[d] = (__float_as_uint(q0) >> 16) | (__float_as_uint(q1) & 0xFFFF0000u);
        s1 += v0 + v1;
        s2 = fmaf(v0, v0, fmaf(v1, v1, s2));
    }
    AH = as_s8(make_uint4(ph[0], ph[1], ph[2], ph[3]));
    AM = as_s8(make_uint4(pm[0], pm[1], pm[2], pm[3]));
    AL = as_s8(make_uint4(pl[0], pl[1], pl[2], pl[3]));
}

#define MFMA6(ACC, AH, AM, AL, BH, BM, BL)                                        \
    ACC = __builtin_amdgcn_mfma_f32_16x16x32_bf16(AH, as_s8(BH), ACC, 0, 0, 0);   \
    ACC = __builtin_amdgcn_mfma_f32_16x16x32_bf16(AH, as_s8(BM), ACC, 0, 0, 0);   \
    ACC = __builtin_amdgcn_mfma_f32_16x16x32_bf16(AM, as_s8(BH), ACC, 0, 0, 0);   \
    ACC = __builtin_amdgcn_mfma_f32_16x16x32_bf16(AH, as_s8(BL), ACC, 0, 0, 0);   \
    ACC = __builtin_amdgcn_mfma_f32_16x16x32_bf16(AM, as_s8(BM), ACC, 0, 0, 0);   \
    ACC = __builtin_amdgcn_mfma_f32_16x16x32_bf16(AL, as_s8(BH), ACC, 0, 0, 0);

// One k-step: issue async stage of step S+1's B into NXT (global_load_lds),
// read B frags of step S from CUR, MFMA, swap A pipeline, barrier (compiler
// emits vmcnt(0)+lgkmcnt(0) drain; the other block on the CU covers it).
#define STEP(S, CUR, NXT, DOSTAGE)                                               \
    {                                                                            \
        if (DOSTAGE) {                                                           \
            _Pragma("unroll")                                                    \
            for (int i = 0; i < 3; ++i) {                                        \
                const int idx = wv * 3 + i;                                      \
                const int term = idx >> 2, nn = idx & 3;                         \
                gld16(bp + term * 32768 + ((S) + 1) * 1024 + nn * 256 + lane * 4,\
                      (NXT) + term * 1024 + nn * 256);                           \
            }                                                                    \
        }                                                                        \
        const int off = (((S) + 2) & 31) * 32;                                   \
        const f32x4 p00 = ntload4(xr0 + off), p01 = ntload4(xr0 + off + 4);      \
        short8 AH0, AM0, AL0;                                                    \
        split8(a00, a01, AH0, AM0, AL0, s1a, s2a);                               \
        _Pragma("unroll")                                                        \
        for (int n = 0; n < 4; ++n) {                                            \
            const uint4 bh = *(const uint4*)((CUR) + n * 256 + lane * 4);        \
            const uint4 bm = *(const uint4*)((CUR) + 1024 + n * 256 + lane * 4); \
            const uint4 bl = *(const uint4*)((CUR) + 2048 + n * 256 + lane * 4); \
            MFMA6(acc[n], AH0, AM0, AL0, bh, bm, bl);                            \
        }                                                                        \
        a00 = b00; a01 = b01; b00 = p00; b01 = p01;                              \
        __syncthreads();                                                         \
    }

// Block = 64 tokens, 4 waves; wave wv owns tokens [wv*16, wv*16+16) (one
// 16-row MFMA group) and iterates the FULL K=1024 (32 k-steps). B-pack is
// shared across waves via a 12 KB x 2 LDS double-buffer staged with async
// global_load_lds. Grid = 512 = 2 independent blocks/CU (8 waves/CU): round
// 2's grid=256 left 1 wave/SIMD, exposing every load latency and barrier
// drain serially — this supplies the second wave/block to overlap them.
__global__ __launch_bounds__(256, 2)
void router_main(const float* __restrict__ x,
                 const float* __restrict__ ws_ro,       // csg/csb
                 const unsigned int* __restrict__ bp,   // packed B frags
                 const float* __restrict__ W2,
                 float* __restrict__ part,
                 float* __restrict__ out) {
    // smem (floats): bstage[2][3072]=6144 | hlds[4][16][65]=4160 | cntl 16
    // w2l (64x16=1024) aliases bstage[0..1024); llds (64x20=1280, padded
    // stride for softmax bank-spread) aliases bstage[1024..2304). Both only
    // live after the main loop's final barrier (bstage dead).
    __shared__ __align__(16) float smem[10320];
    float* bstage = smem;
    float* hlds   = smem + 6144;
    float* cntl   = smem + 10304;
    float* w2l    = smem;
    float* llds   = smem + 1024;

    const int t    = threadIdx.x;
    const int wv   = t >> 6;
    const int lane = t & 63;
    const int q = lane >> 4, c = lane & 15;
    const int tok0 = blockIdx.x * 64;
    const int tokw = tok0 + wv * 16;

    if (t < 16) cntl[t] = 0.f;

    // per-lane colsum constants (col = n*16 + c) — registers, no LDS staging
    float csg[4], csb[4];
#pragma unroll
    for (int n = 0; n < 4; ++n) {
        csg[n] = ws_ro[CS_F + n * 16 + c];
        csb[n] = ws_ro[CS_F + 64 + n * 16 + c];
    }

    const float* xr0 = x + (size_t)(tokw + c) * DDIM + q * 8;

    float* const bufA = bstage;
    float* const bufB = bstage + 3072;

    // prologue: async-stage step 0's B (12 KB) into bufA: 4 waves x 3 chunks
    {
#pragma unroll
        for (int i = 0; i < 3; ++i) {
            const int idx = wv * 3 + i;
            const int term = idx >> 2, nn = idx & 3;
            gld16(bp + term * 32768 + nn * 256 + lane * 4,
                  bufA + term * 1024 + nn * 256);
        }
    }

    f32x4 acc[4] = {{0.f,0.f,0.f,0.f},{0.f,0.f,0.f,0.f},{0.f,0.f,0.f,0.f},{0.f,0.f,0.f,0.f}};
    float s1a = 0.f, s2a = 0.f;

    // A: 2-step register pipeline, nontemporal (protect L2/L3 for B-pack)
    f32x4 a00 = ntload4(xr0),      a01 = ntload4(xr0 + 4);
    f32x4 b00 = ntload4(xr0 + 32), b01 = ntload4(xr0 + 36);

    __syncthreads();   // bufA visible (vmcnt drain + barrier)

#pragma unroll 1
    for (int s2i = 0; s2i < 16; ++s2i) {
        const int s = s2i * 2;
        STEP(s,     bufA, bufB, 1)
        STEP(s + 1, bufB, bufA, (s2i < 15))
    }

    // LN-stat q-reduction: lane (q,c) holds k-quarter partials for token
    // tokw+c; xor 16/32 combines the 4 q replicas -> full-K stats at lane c.
    s1a += __shfl_xor(s1a, 16, 64); s1a += __shfl_xor(s1a, 32, 64);
    s2a += __shfl_xor(s2a, 16, 64); s2a += __shfl_xor(s2a, 32, 64);

    // W2 -> LDS (row-major 64x16), aliases bufA head (dead after main loop)
    *(float4*)(w2l + t * 4) = *(const float4*)(W2 + t * 4);

    // stats redistribution (token tt stats live at lane tt) + LN fold +
    // exact GELU, straight from accumulator registers -> h to LDS.
    {
        float* hw = hlds + wv * 1040;
#pragma unroll
        for (int r = 0; r < 4; ++r) {
            const int tt = q * 4 + r;
            const float S1A = __shfl(s1a, tt, 64), S2A = __shfl(s2a, tt, 64);
            const float muA = S1A * (1.0f / 1024.0f);
            const float rsA = 1.0f / sqrtf(S2A * (1.0f / 1024.0f) - muA * muA + LN_EPS);
#pragma unroll
            for (int n = 0; n < 4; ++n) {
                const float preA = rsA * (acc[n][r] - muA * csg[n]) + csb[n];
                hw[tt * 65 + n * 16 + c] =
                    0.5f * preA * (1.0f + erff(preA * 0.70710678118654752f));
            }
        }
    }
    __syncthreads();

    // logits: thread -> (token m2 = t>>2, 4 nb cols). w2l reads hit 4
    // distinct banks (broadcast within groups); hrow reads stride-65.
    {
        const int m2 = t >> 2, o = (t & 3) * 4;
        const float* hrow = hlds + (m2 >> 4) * 1040 + (m2 & 15) * 65;
        f32x4 L0 = {0.f, 0.f, 0.f, 0.f};
#pragma unroll 8
        for (int j = 0; j < 64; ++j) {
            L0 += *(const f32x4*)(w2l + j * 16 + o) * hrow[j];
        }
        *(f32x4*)(llds + m2 * 20 + o) = L0 * 0.5f;   // /TEMP
    }
    __syncthreads();

    // softmax + top-2 + outputs (one thread per token; 64 tokens/block)
    if (t < 64) {
        float p[16];
        float mx = -1e30f;
#pragma unroll
        for (int i = 0; i < NB; ++i) { p[i] = llds[t * 20 + i]; mx = fmaxf(mx, p[i]); }
        float ssum = 0.f;
#pragma unroll
        for (int i = 0; i < NB; ++i) { p[i] = expf(p[i] - mx); ssum += p[i]; }
        const float inv = 1.0f / ssum;
#pragma unroll
        for (int i = 0; i < NB; ++i) { p[i] *= inv; llds[t * 20 + i] = p[i]; }

        float* po = out + (size_t)(tok0 + t) * NB;
#pragma unroll
        for (int u = 0; u < 4; ++u) {
            float4 v; v.x = p[u*4]; v.y = p[u*4+1]; v.z = p[u*4+2]; v.w = p[u*4+3];
            *(float4*)(po + u * 4) = v;
        }

        float b0 = -1.f, b1 = -1.f;
        int i0 = 0, i1 = 0;
#pragma unroll
        for (int i = 0; i < NB; ++i) {
            if (p[i] > b0)      { b1 = b0; i1 = i0; b0 = p[i]; i0 = i; }
            else if (p[i] > b1) { b1 = p[i]; i1 = i; }
        }
        const float wsum = b0 + b1 + 1e-8f;
        out[IDX_OFF + (size_t)(tok0 + t) * 2]     = (float)i0;
        out[IDX_OFF + (size_t)(tok0 + t) * 2 + 1] = (float)i1;
        out[WT_OFF + (size_t)(tok0 + t) * 2]      = b0 / wsum;
        out[WT_OFF + (size_t)(tok0 + t) * 2 + 1]  = b1 / wsum;
        atomicAdd(&cntl[i0], 1.0f);
        atomicAdd(&cntl[i1], 1.0f);
    }
    __syncthreads();

    // per-block partials (plain stores; aux reads after dispatch boundary)
    if (t < 16) {
        float ps = 0.f;
        for (int m = 0; m < 64; ++m) ps += llds[m * 20 + t];
        part[(size_t)blockIdx.x * 32 + t]      = cntl[t];
        part[(size_t)blockIdx.x * 32 + 16 + t] = ps;
    }
}

__global__ void aux_kernel(const float* __restrict__ part,
                           float* __restrict__ gacc,
                           float* __restrict__ out) {
    __shared__ float red[8][32];
    __shared__ float flag;
    const int t = threadIdx.x;          // 256
    const int b = blockIdx.x;           // 32 blocks x 16 rows (512 total)
    const int i = t & 31, rr = t >> 5;  // rr 0..7
    const int r0 = b * 16 + rr;
    red[rr][i] = part[(size_t)r0 * 32 + i] + part[(size_t)(r0 + 8) * 32 + i];
    __syncthreads();
    if (t < 32) {
        float tot = 0.f;
#pragma unroll
        for (int p = 0; p < 8; ++p) tot += red[p][t];
        atomicAdd(&gacc[t], tot);
    }
    __syncthreads();
    if (t == 0) {
        __threadfence();
        const unsigned int old = atomicAdd((unsigned int*)(gacc + 32), 1u);
        flag = (old == 31u) ? 1.f : 0.f;
    }
    __syncthreads();
    if (flag != 0.f) {
        if (t < 32) red[0][t] = atomicAdd(&gacc[t], 0.0f);   // coherent read
        __syncthreads();
        if (t == 0) {
            float a = 0.f;
            for (int k = 0; k < NB; ++k) {
                const float f = red[0][k] / (65536.0f + 1e-8f);
                const float P = red[0][16 + k] * (1.0f / 32768.0f);
                a += f * P;
            }
            out[AUX_OFF] = 16.0f * a;
        }
    }
}

extern "C" void kernel_launch(void* const* d_in, const int* in_sizes, int n_in,
                              void* d_out, int out_size, void* d_ws, size_t ws_size,
                              hipStream_t stream) {
    const float* x     = (const float*)d_in[0];
    const float* gamma = (const float*)d_in[1];
    const float* beta  = (const float*)d_in[2];
    const float* W1    = (const float*)d_in[3];
    const float* W2    = (const float*)d_in[4];
    float* out = (float*)d_out;
    float* ws  = (float*)d_ws;

    (void)hipMemsetAsync(ws, 0, 192 * sizeof(float), stream);  // accums + counter + cs
    pack_kernel<<<32, 256, 0, stream>>>(W1, gamma, beta, ws);
    router_main<<<NTOK / 64, 256, 0, stream>>>(x, ws, (const unsigned int*)(ws + BP_F),
                                               W2, ws + PART_F, out);
    aux_kernel<<<32, 256, 0, stream>>>(ws + PART_F, ws, out);
}